// Round 5
// baseline (140.377 us; speedup 1.0000x reference)
//
#include <hip/hip_runtime.h>

// ConvCaps EM-routing, MI355X. 392 independent problems, one 512-thread block each.
// Thread = (o = t&31 out-cap, kc = t>>5 of 16 k-chunks, 18 k each).
// __launch_bounds__(512,4) -> 128 VGPR cap. Grid is only 392 blocks -> ~25%
// occupancy, unfixable (rounds 1/3: more threads or dual-k state => scratch
// spill catastrophe). Kernel is STALL-bound (VALUBusy 43% constant across
// instruction-count changes), dominated by exposed per-k W(L2) latency: the
// compiler does no cross-iteration load motion (left 64 VGPRs unused).
// This version: explicit 1-deep software pipeline of the Wg stream (raw float4
// double-buffer, prefetch issued right after votes consume current W; unpack
// at use so the waitcnt lands in the next body), and the per-k redmax is
// replaced by the iteration-constant shift Mb = max_o(base) (softmax is
// shift-invariant; lnp <= base <= Mb so exp never overflows).
// Fused E+M: votes recomputed 3x (M0, E0+M1, E1+M2) using unnormalized
// moments  mean = S(uv)/(rs+eps), var = S(uv^2)/(rs+eps) - m^2(2-S1),
// u_k = softmax_o(ln_ap)*c_k, c_k = a/(a+eps). r-matrix never materialized.
// Packed fp32 (v_pk_*) on the vote/sacc/accum math; DPP+swizzle reduces.

namespace {

constexpr int NKK = 288;
constexpr float EPSF = 1e-8f;
constexpr float LN2PI = 1.8378770664093453f;

typedef float f32x2 __attribute__((ext_vector_type(2)));

__device__ __forceinline__ float fastrcp(float x) { return __builtin_amdgcn_rcpf(x); }
__device__ __forceinline__ f32x2 splat2(float x) { f32x2 r; r.x = x; r.y = x; return r; }
__device__ __forceinline__ f32x2 fma2(f32x2 a, f32x2 b, f32x2 c) {
    return __builtin_elementwise_fma(a, b, c);
}
__device__ __forceinline__ f32x2 lo2(float4 v) { f32x2 r; r.x = v.x; r.y = v.y; return r; }
__device__ __forceinline__ f32x2 hi2(float4 v) { f32x2 r; r.x = v.z; r.y = v.w; return r; }

// DPP lane permute (VALU pipe). CTRL: 0xB1=quad_perm xor1, 0x4E=quad_perm xor2,
// 0x141=row_half_mirror (xor7), 0x140=row_mirror (xor15).
template <int CTRL>
__device__ __forceinline__ float dppf(float x) {
    return __int_as_float(__builtin_amdgcn_update_dpp(
        __float_as_int(x), __float_as_int(x), CTRL, 0xF, 0xF, false));
}
// ds_swizzle xor16 within each 32-lane group (bitmode: xor=16, and=0x1F).
__device__ __forceinline__ float swz16(float x) {
    return __int_as_float(__builtin_amdgcn_ds_swizzle(__float_as_int(x), 0x401F));
}

// Reduce over the 32-lane group (lanes 0-31 / 32-63 independently).
// XOR-mask basis {1,2,7,15,16} spans bits 0..4 -> valid butterfly.
__device__ __forceinline__ float redmax32(float v) {
    v = fmaxf(v, dppf<0xB1>(v));
    v = fmaxf(v, dppf<0x4E>(v));
    v = fmaxf(v, dppf<0x141>(v));
    v = fmaxf(v, dppf<0x140>(v));
    v = fmaxf(v, swz16(v));
    return v;
}
__device__ __forceinline__ float redsum32(float v) {
    v += dppf<0xB1>(v);
    v += dppf<0x4E>(v);
    v += dppf<0x141>(v);
    v += dppf<0x140>(v);
    v += swz16(v);
    return v;
}

__global__ __launch_bounds__(512, 4)
void caps_em_kernel(const float* __restrict__ x,
                    const float* __restrict__ Wg,
                    const float* __restrict__ bu,
                    const float* __restrict__ ba,
                    float* __restrict__ out)
{
    // LDS: 18432 + 1152 + 33792 + 2176 + 2176 + 256 = 57984 B -> 2 blocks/CU
    __shared__ float p4[NKK * 16];       // pose fragments [k*16+p]
    __shared__ float cIn[NKK];           // a/(a+eps)
    __shared__ float scr[8 * 32 * 33];   // [g][o][ Sv(16) | Sv2(16) | S0 ]
    __shared__ float meanS[32 * 17];     // mean[o*17+p]  (stride 17: conflict-free)
    __shared__ float i2vS[32 * 17];      // 1/(2*std^2)
    __shared__ float actS[32];
    __shared__ float baseS[32];          // log(act) - sum_p log std - 8*ln2pi

    const int n = blockIdx.x;
    const int t = threadIdx.x;

    // ---- gather poses: flat view of tiled (B,kh,kw,oh,ow,512) ----
    for (int idx = t; idx < NKK * 16; idx += 512) {
        unsigned g = (unsigned)n * 4608u + (unsigned)idx;
        unsigned c = g & 511u, rest = g >> 9;
        unsigned ow = rest % 7u; rest /= 7u;
        unsigned oh = rest % 7u; rest /= 7u;
        unsigned kw = rest % 3u; rest /= 3u;
        unsigned kh = rest % 3u;
        unsigned b  = rest / 3u;
        p4[idx] = x[((b*16u + 2u*oh + kh)*16u + 2u*ow + kw)*544u + c];
    }
    // ---- gather acts -> c_k ----
    for (int idx = t; idx < NKK; idx += 512) {
        unsigned g = (unsigned)n * 288u + (unsigned)idx;
        unsigned c = g & 31u, rest = g >> 5;
        unsigned ow = rest % 7u; rest /= 7u;
        unsigned oh = rest % 7u; rest /= 7u;
        unsigned kw = rest % 3u; rest /= 3u;
        unsigned kh = rest % 3u;
        unsigned b  = rest / 3u;
        const float a = x[((b*16u + 2u*oh + kh)*16u + 2u*ow + kw)*544u + 512u + c];
        cIn[idx] = a / (a + EPSF);
    }
    __syncthreads();

    const int o  = t & 31;    // out-cap (== lane&31)
    const int kc = t >> 5;    // k-chunk 0..15 (18 k each)
    const int oo = t >> 4;    // reducer row 0..31
    const int pp = t & 15;    // reducer col 0..15

    float lam = 1.0e-3f;

// Load P[16] scalars from p4 (LDS, broadcast within half-wave).
#define LOAD_P(K_)                                                         \
    float P[16];                                                           \
    {                                                                      \
        const float4 p0 = *(const float4*)&p4[(K_)*16 + 0];                \
        const float4 p1 = *(const float4*)&p4[(K_)*16 + 4];                \
        const float4 p2 = *(const float4*)&p4[(K_)*16 + 8];                \
        const float4 p3 = *(const float4*)&p4[(K_)*16 + 12];               \
        P[0]=p0.x; P[1]=p0.y; P[2]=p0.z; P[3]=p0.w;                        \
        P[4]=p1.x; P[5]=p1.y; P[6]=p1.z; P[7]=p1.w;                        \
        P[8]=p2.x; P[9]=p2.y; P[10]=p2.z; P[11]=p2.w;                      \
        P[12]=p3.x; P[13]=p3.y; P[14]=p3.z; P[15]=p3.w;                    \
    }

// Prefetch W row for K_ into raw float4 regs (no unpack -> no waitcnt here).
#define LOAD_W(WD, K_)                                                     \
    {                                                                      \
        const float4* wp_ = (const float4*)&Wg[((K_)*32 + o)*16];          \
        WD[0] = wp_[0]; WD[1] = wp_[1]; WD[2] = wp_[2]; WD[3] = wp_[3];    \
    }

// Votes from P x WCUR (unpack at use). v2[q], q = i*2+h.
#define VOTES(WCUR, V2)                                                    \
    _Pragma("unroll")                                                      \
    for (int i = 0; i < 4; ++i) {                                          \
        _Pragma("unroll")                                                  \
        for (int h = 0; h < 2; ++h) {                                      \
            const f32x2 w0 = (h == 0) ? lo2(WCUR[0]) : hi2(WCUR[0]);       \
            const f32x2 w1 = (h == 0) ? lo2(WCUR[1]) : hi2(WCUR[1]);       \
            const f32x2 w2 = (h == 0) ? lo2(WCUR[2]) : hi2(WCUR[2]);       \
            const f32x2 w3 = (h == 0) ? lo2(WCUR[3]) : hi2(WCUR[3]);       \
            f32x2 acc = splat2(P[i*4]) * w0;                               \
            acc = fma2(splat2(P[i*4+1]), w1, acc);                         \
            acc = fma2(splat2(P[i*4+2]), w2, acc);                         \
            acc = fma2(splat2(P[i*4+3]), w3, acc);                         \
            V2[i*2 + h] = acc;                                             \
        }                                                                  \
    }

// M0 body: uniform r. Uses WCUR, prefetches KN_ into WNXT.
#define M0_BODY(K_, WCUR, KN_, WNXT)                                       \
    {                                                                      \
        const int k_ = (K_);                                               \
        LOAD_P(k_)                                                         \
        f32x2 v2[8];                                                       \
        VOTES(WCUR, v2)                                                    \
        LOAD_W(WNXT, (KN_))                                                \
        const float w_ = cIn[k_] * 0.03125f;                               \
        const f32x2 w2_ = splat2(w_);                                      \
        S0 += w_;                                                          \
        _Pragma("unroll")                                                  \
        for (int q = 0; q < 8; ++q) {                                      \
            const f32x2 wv = w2_ * v2[q];                                  \
            Svp[q] += wv;                                                  \
            Sv2p[q] = fma2(wv, v2[q], Sv2p[q]);                            \
        }                                                                  \
    }

// E body: fused E(prev stats)+M accumulate. Uses WCUR, prefetches KN_.
#define E_BODY(K_, WCUR, KN_, WNXT)                                        \
    {                                                                      \
        const int k_ = (K_);                                               \
        LOAD_P(k_)                                                         \
        f32x2 v2[8];                                                       \
        VOTES(WCUR, v2)                                                    \
        LOAD_W(WNXT, (KN_))                                                \
        f32x2 saA = splat2(0.f), saB = splat2(0.f);                        \
        _Pragma("unroll")                                                  \
        for (int q = 0; q < 8; ++q) {                                      \
            const f32x2 d = v2[q] - M2[q];                                 \
            if (q & 1) saB = fma2(d * d, I2[q], saB);                      \
            else       saA = fma2(d * d, I2[q], saA);                      \
        }                                                                  \
        const f32x2 sab = saA + saB;                                       \
        const float lnp = base - (sab.x + sab.y);                          \
        const float e  = __expf(lnp - Mb);                                 \
        const float ss = redsum32(e);                                      \
        const float u = e * fastrcp(ss) * cIn[k_];                         \
        S0 += u;                                                           \
        const f32x2 u2 = splat2(u);                                        \
        _Pragma("unroll")                                                  \
        for (int q = 0; q < 8; ++q) {                                      \
            const f32x2 uv = u2 * v2[q];                                   \
            Svp[q] += uv;                                                  \
            Sv2p[q] = fma2(uv, v2[q], Sv2p[q]);                            \
        }                                                                  \
    }

    for (int it = 0; it < 3; ++it) {
        lam += 1.0e-4f;

        float S0 = 0.f;
        f32x2 Svp[8], Sv2p[8];
        #pragma unroll
        for (int q = 0; q < 8; ++q) { Svp[q] = splat2(0.f); Sv2p[q] = splat2(0.f); }

        const int k0 = kc * 18;
        float4 Wa[4], Wb[4];
        LOAD_W(Wa, k0)

        if (it == 0) {
            // ---- M0: uniform r -> u_k = c_k/32 (same for all o) ----
            #pragma unroll 1
            for (int kk = 0; kk < 18; kk += 2) {
                const int k = k0 + kk;
                M0_BODY(k, Wa, k + 1, Wb)
                int kn2 = k + 2; if (kn2 >= NKK) kn2 = 0;
                M0_BODY(k + 1, Wb, kn2, Wa)
            }
        } else {
            // ---- fused E(prev stats) + M accumulate, W software-pipelined ----
            f32x2 M2[8], I2[8];
            #pragma unroll
            for (int q = 0; q < 8; ++q) {
                f32x2 m; m.x = meanS[o*17 + 2*q]; m.y = meanS[o*17 + 2*q + 1];
                f32x2 iv; iv.x = i2vS[o*17 + 2*q]; iv.y = i2vS[o*17 + 2*q + 1];
                M2[q] = m; I2[q] = iv;
            }
            const float base = baseS[o];
            const float Mb = redmax32(base);   // iteration-constant softmax shift
            #pragma unroll 1
            for (int kk = 0; kk < 18; kk += 2) {
                const int k = k0 + kk;
                E_BODY(k, Wa, k + 1, Wb)
                int kn2 = k + 2; if (kn2 >= NKK) kn2 = 0;
                E_BODY(k + 1, Wb, kn2, Wa)
            }
        }

        // ---- combine kc pairs (partner lane^32, same wave) -> 8 groups ----
        S0 += __shfl_xor(S0, 32, 64);
        #pragma unroll
        for (int q = 0; q < 8; ++q) {
            f32x2 ta, tb;
            ta.x = __shfl_xor(Svp[q].x, 32, 64);
            ta.y = __shfl_xor(Svp[q].y, 32, 64);
            tb.x = __shfl_xor(Sv2p[q].x, 32, 64);
            tb.y = __shfl_xor(Sv2p[q].y, 32, 64);
            Svp[q] += ta;
            Sv2p[q] += tb;
        }
        if ((kc & 1) == 0) {
            float* row = &scr[((kc >> 1)*32 + o)*33];
            #pragma unroll
            for (int q = 0; q < 8; ++q) {
                row[2*q]      = Svp[q].x;  row[2*q + 1]      = Svp[q].y;
                row[16 + 2*q] = Sv2p[q].x; row[16 + 2*q + 1] = Sv2p[q].y;
            }
            row[32] = S0;
        }
        __syncthreads();

        // ---- reduce 8 groups + stats; thread t handles (oo, pp) ----
        {
            float sm = 0.f, s2 = 0.f, rs = 0.f;
            #pragma unroll
            for (int q = 0; q < 8; ++q) {
                const int b0 = (q*32 + oo)*33;
                sm += scr[b0 + pp];
                s2 += scr[b0 + 16 + pp];
                rs += scr[b0 + 32];
            }
            const float inv = 1.0f / (rs + EPSF);
            const float S1  = rs * inv;
            const float m   = sm * inv;
            float var = s2 * inv - m*m*(2.0f - S1);
            var = fmaxf(var, 0.0f) + EPSF;          // std^2 (+eps inside sqrt)
            meanS[oo*17 + pp] = m;
            i2vS [oo*17 + pp] = 0.5f / var;
            scr[oo*33 + pp] = 0.5f * __logf(var);   // log std; q=0 slot owned by this thread
        }
        __syncthreads();
        if (t < 32) {
            float lsum = 0.f;
            #pragma unroll
            for (int p = 0; p < 16; ++p) lsum += scr[t*33 + p];
            float rs = 0.f;
            #pragma unroll
            for (int q = 0; q < 8; ++q) rs += scr[(q*32 + t)*33 + 32];
            const float cost = (16.0f * bu[t] + lsum) * rs;
            const float ao   = 1.0f / (1.0f + __expf(-lam * (ba[t] - cost)));
            actS[t]  = ao;
            baseS[t] = -lsum - 8.0f*LN2PI + __logf(ao);
        }
        __syncthreads();
    }

#undef LOAD_P
#undef LOAD_W
#undef VOTES
#undef M0_BODY
#undef E_BODY

    // ---- output: [mean(512) | act(32)] per n ----
    for (int idx = t; idx < 544; idx += 512) {
        const float v = (idx < 512) ? meanS[(idx >> 4)*17 + (idx & 15)]
                                    : actS[idx - 512];
        out[n*544 + idx] = v;
    }
}

} // namespace

extern "C" void kernel_launch(void* const* d_in, const int* in_sizes, int n_in,
                              void* d_out, int out_size, void* d_ws, size_t ws_size,
                              hipStream_t stream) {
    (void)in_sizes; (void)n_in; (void)out_size; (void)d_ws; (void)ws_size;
    const float* x  = (const float*)d_in[0];
    const float* W  = (const float*)d_in[1];
    const float* bu = (const float*)d_in[2];
    const float* ba = (const float*)d_in[3];
    float* out = (float*)d_out;
    caps_em_kernel<<<dim3(392), dim3(512), 0, stream>>>(x, W, bu, ba, out);
}

// Round 6
// 140.373 us; speedup vs baseline: 1.0000x; 1.0000x over previous
//
#include <hip/hip_runtime.h>

// ConvCaps EM-routing, MI355X. 392 independent problems, one 512-thread block each.
// Thread = (o = t&31 out-cap, kc = t>>5 of 16 k-chunks, 18 k each).
//
// KEY: amdgpu_waves_per_eu(4,4). With plain __launch_bounds__(512,4) the LLVM
// allocator still targets MAX occupancy (8 waves/EU = 64 VGPR) and SPILLS
// instead of relaxing to the declared minimum -- all six prior runs report
// VGPR_Count=64, including the spilling ones (FETCH 23-675 MB). Pinning
// min=max=4 waves/EU makes the true budget 128 VGPR. Occupancy is unchanged:
// LDS (58 KB -> 2 blocks/CU) and the 392-block grid already cap at 4 waves/EU.
//
// Software pipeline: raw float4 W double-buffer; prefetch of W(k+1) issued
// right after votes consume W(k) (P/Wcur dead), unpack at use so the waitcnt
// lands in the next body. Per-k redmax replaced by the iteration-constant
// shift Mb = max_o(base) (softmax shift-invariant; lnp <= base <= Mb).
// Fused E+M: votes recomputed 3x (M0, E0+M1, E1+M2) using unnormalized
// moments  mean = S(uv)/(rs+eps), var = S(uv^2)/(rs+eps) - m^2(2-S1),
// u_k = softmax_o(ln_ap)*c_k, c_k = a/(a+eps). r-matrix never materialized.
// Packed fp32 (v_pk_*) on vote/sacc/accum math; DPP+swizzle 32-lane reduces.

namespace {

constexpr int NKK = 288;
constexpr float EPSF = 1e-8f;
constexpr float LN2PI = 1.8378770664093453f;

typedef float f32x2 __attribute__((ext_vector_type(2)));

__device__ __forceinline__ float fastrcp(float x) { return __builtin_amdgcn_rcpf(x); }
__device__ __forceinline__ f32x2 splat2(float x) { f32x2 r; r.x = x; r.y = x; return r; }
__device__ __forceinline__ f32x2 fma2(f32x2 a, f32x2 b, f32x2 c) {
    return __builtin_elementwise_fma(a, b, c);
}
__device__ __forceinline__ f32x2 lo2(float4 v) { f32x2 r; r.x = v.x; r.y = v.y; return r; }
__device__ __forceinline__ f32x2 hi2(float4 v) { f32x2 r; r.x = v.z; r.y = v.w; return r; }

// DPP lane permute (VALU pipe). CTRL: 0xB1=quad_perm xor1, 0x4E=quad_perm xor2,
// 0x141=row_half_mirror (xor7), 0x140=row_mirror (xor15).
template <int CTRL>
__device__ __forceinline__ float dppf(float x) {
    return __int_as_float(__builtin_amdgcn_update_dpp(
        __float_as_int(x), __float_as_int(x), CTRL, 0xF, 0xF, false));
}
// ds_swizzle xor16 within each 32-lane group (bitmode: xor=16, and=0x1F).
__device__ __forceinline__ float swz16(float x) {
    return __int_as_float(__builtin_amdgcn_ds_swizzle(__float_as_int(x), 0x401F));
}

// Reduce over the 32-lane group (lanes 0-31 / 32-63 independently).
// XOR-mask basis {1,2,7,15,16} spans bits 0..4 -> valid butterfly.
__device__ __forceinline__ float redmax32(float v) {
    v = fmaxf(v, dppf<0xB1>(v));
    v = fmaxf(v, dppf<0x4E>(v));
    v = fmaxf(v, dppf<0x141>(v));
    v = fmaxf(v, dppf<0x140>(v));
    v = fmaxf(v, swz16(v));
    return v;
}
__device__ __forceinline__ float redsum32(float v) {
    v += dppf<0xB1>(v);
    v += dppf<0x4E>(v);
    v += dppf<0x141>(v);
    v += dppf<0x140>(v);
    v += swz16(v);
    return v;
}

__global__ __launch_bounds__(512)
__attribute__((amdgpu_waves_per_eu(4, 4)))
void caps_em_kernel(const float* __restrict__ x,
                    const float* __restrict__ Wg,
                    const float* __restrict__ bu,
                    const float* __restrict__ ba,
                    float* __restrict__ out)
{
    // LDS: 18432 + 1152 + 33792 + 2176 + 2176 + 256 = 57984 B -> 2 blocks/CU
    __shared__ float p4[NKK * 16];       // pose fragments [k*16+p]
    __shared__ float cIn[NKK];           // a/(a+eps)
    __shared__ float scr[8 * 32 * 33];   // [g][o][ Sv(16) | Sv2(16) | S0 ]
    __shared__ float meanS[32 * 17];     // mean[o*17+p]  (stride 17: conflict-free)
    __shared__ float i2vS[32 * 17];      // 1/(2*std^2)
    __shared__ float actS[32];
    __shared__ float baseS[32];          // log(act) - sum_p log std - 8*ln2pi

    const int n = blockIdx.x;
    const int t = threadIdx.x;

    // ---- gather poses: flat view of tiled (B,kh,kw,oh,ow,512) ----
    for (int idx = t; idx < NKK * 16; idx += 512) {
        unsigned g = (unsigned)n * 4608u + (unsigned)idx;
        unsigned c = g & 511u, rest = g >> 9;
        unsigned ow = rest % 7u; rest /= 7u;
        unsigned oh = rest % 7u; rest /= 7u;
        unsigned kw = rest % 3u; rest /= 3u;
        unsigned kh = rest % 3u;
        unsigned b  = rest / 3u;
        p4[idx] = x[((b*16u + 2u*oh + kh)*16u + 2u*ow + kw)*544u + c];
    }
    // ---- gather acts -> c_k ----
    for (int idx = t; idx < NKK; idx += 512) {
        unsigned g = (unsigned)n * 288u + (unsigned)idx;
        unsigned c = g & 31u, rest = g >> 5;
        unsigned ow = rest % 7u; rest /= 7u;
        unsigned oh = rest % 7u; rest /= 7u;
        unsigned kw = rest % 3u; rest /= 3u;
        unsigned kh = rest % 3u;
        unsigned b  = rest / 3u;
        const float a = x[((b*16u + 2u*oh + kh)*16u + 2u*ow + kw)*544u + 512u + c];
        cIn[idx] = a / (a + EPSF);
    }
    __syncthreads();

    const int o  = t & 31;    // out-cap (== lane&31)
    const int kc = t >> 5;    // k-chunk 0..15 (18 k each)
    const int oo = t >> 4;    // reducer row 0..31
    const int pp = t & 15;    // reducer col 0..15

    float lam = 1.0e-3f;

// Load P[16] scalars from p4 (LDS, broadcast within half-wave).
#define LOAD_P(K_)                                                         \
    float P[16];                                                           \
    {                                                                      \
        const float4 p0 = *(const float4*)&p4[(K_)*16 + 0];                \
        const float4 p1 = *(const float4*)&p4[(K_)*16 + 4];                \
        const float4 p2 = *(const float4*)&p4[(K_)*16 + 8];                \
        const float4 p3 = *(const float4*)&p4[(K_)*16 + 12];               \
        P[0]=p0.x; P[1]=p0.y; P[2]=p0.z; P[3]=p0.w;                        \
        P[4]=p1.x; P[5]=p1.y; P[6]=p1.z; P[7]=p1.w;                        \
        P[8]=p2.x; P[9]=p2.y; P[10]=p2.z; P[11]=p2.w;                      \
        P[12]=p3.x; P[13]=p3.y; P[14]=p3.z; P[15]=p3.w;                    \
    }

// Prefetch W row for K_ into raw float4 regs (no unpack -> no waitcnt here).
#define LOAD_W(WD, K_)                                                     \
    {                                                                      \
        const float4* wp_ = (const float4*)&Wg[((K_)*32 + o)*16];          \
        WD[0] = wp_[0]; WD[1] = wp_[1]; WD[2] = wp_[2]; WD[3] = wp_[3];    \
    }

// Votes from P x WCUR (unpack at use). v2[q], q = i*2+h.
#define VOTES(WCUR, V2)                                                    \
    _Pragma("unroll")                                                      \
    for (int i = 0; i < 4; ++i) {                                          \
        _Pragma("unroll")                                                  \
        for (int h = 0; h < 2; ++h) {                                      \
            const f32x2 w0 = (h == 0) ? lo2(WCUR[0]) : hi2(WCUR[0]);       \
            const f32x2 w1 = (h == 0) ? lo2(WCUR[1]) : hi2(WCUR[1]);       \
            const f32x2 w2 = (h == 0) ? lo2(WCUR[2]) : hi2(WCUR[2]);       \
            const f32x2 w3 = (h == 0) ? lo2(WCUR[3]) : hi2(WCUR[3]);       \
            f32x2 acc = splat2(P[i*4]) * w0;                               \
            acc = fma2(splat2(P[i*4+1]), w1, acc);                         \
            acc = fma2(splat2(P[i*4+2]), w2, acc);                         \
            acc = fma2(splat2(P[i*4+3]), w3, acc);                         \
            V2[i*2 + h] = acc;                                             \
        }                                                                  \
    }

// M0 body: uniform r. Uses WCUR, prefetches KN_ into WNXT.
#define M0_BODY(K_, WCUR, KN_, WNXT)                                       \
    {                                                                      \
        const int k_ = (K_);                                               \
        LOAD_P(k_)                                                         \
        f32x2 v2[8];                                                       \
        VOTES(WCUR, v2)                                                    \
        LOAD_W(WNXT, (KN_))                                                \
        const float w_ = cIn[k_] * 0.03125f;                               \
        const f32x2 w2_ = splat2(w_);                                      \
        S0 += w_;                                                          \
        _Pragma("unroll")                                                  \
        for (int q = 0; q < 8; ++q) {                                      \
            const f32x2 wv = w2_ * v2[q];                                  \
            Svp[q] += wv;                                                  \
            Sv2p[q] = fma2(wv, v2[q], Sv2p[q]);                            \
        }                                                                  \
    }

// E body: fused E(prev stats)+M accumulate. Uses WCUR, prefetches KN_.
#define E_BODY(K_, WCUR, KN_, WNXT)                                        \
    {                                                                      \
        const int k_ = (K_);                                               \
        LOAD_P(k_)                                                         \
        f32x2 v2[8];                                                       \
        VOTES(WCUR, v2)                                                    \
        LOAD_W(WNXT, (KN_))                                                \
        f32x2 saA = splat2(0.f), saB = splat2(0.f);                        \
        _Pragma("unroll")                                                  \
        for (int q = 0; q < 8; ++q) {                                      \
            const f32x2 d = v2[q] - M2[q];                                 \
            if (q & 1) saB = fma2(d * d, I2[q], saB);                      \
            else       saA = fma2(d * d, I2[q], saA);                      \
        }                                                                  \
        const f32x2 sab = saA + saB;                                       \
        const float lnp = base - (sab.x + sab.y);                          \
        const float e  = __expf(lnp - Mb);                                 \
        const float ss = redsum32(e);                                      \
        const float u = e * fastrcp(ss) * cIn[k_];                         \
        S0 += u;                                                           \
        const f32x2 u2 = splat2(u);                                        \
        _Pragma("unroll")                                                  \
        for (int q = 0; q < 8; ++q) {                                      \
            const f32x2 uv = u2 * v2[q];                                   \
            Svp[q] += uv;                                                  \
            Sv2p[q] = fma2(uv, v2[q], Sv2p[q]);                            \
        }                                                                  \
    }

    for (int it = 0; it < 3; ++it) {
        lam += 1.0e-4f;

        float S0 = 0.f;
        f32x2 Svp[8], Sv2p[8];
        #pragma unroll
        for (int q = 0; q < 8; ++q) { Svp[q] = splat2(0.f); Sv2p[q] = splat2(0.f); }

        const int k0 = kc * 18;
        float4 Wa[4], Wb[4];
        LOAD_W(Wa, k0)

        if (it == 0) {
            // ---- M0: uniform r -> u_k = c_k/32 (same for all o) ----
            #pragma unroll 1
            for (int kk = 0; kk < 18; kk += 2) {
                const int k = k0 + kk;
                M0_BODY(k, Wa, k + 1, Wb)
                int kn2 = k + 2; if (kn2 >= NKK) kn2 = 0;
                M0_BODY(k + 1, Wb, kn2, Wa)
            }
        } else {
            // ---- fused E(prev stats) + M accumulate, W software-pipelined ----
            f32x2 M2[8], I2[8];
            #pragma unroll
            for (int q = 0; q < 8; ++q) {
                f32x2 m; m.x = meanS[o*17 + 2*q]; m.y = meanS[o*17 + 2*q + 1];
                f32x2 iv; iv.x = i2vS[o*17 + 2*q]; iv.y = i2vS[o*17 + 2*q + 1];
                M2[q] = m; I2[q] = iv;
            }
            const float base = baseS[o];
            const float Mb = redmax32(base);   // iteration-constant softmax shift
            #pragma unroll 1
            for (int kk = 0; kk < 18; kk += 2) {
                const int k = k0 + kk;
                E_BODY(k, Wa, k + 1, Wb)
                int kn2 = k + 2; if (kn2 >= NKK) kn2 = 0;
                E_BODY(k + 1, Wb, kn2, Wa)
            }
        }

        // ---- combine kc pairs (partner lane^32, same wave) -> 8 groups ----
        S0 += __shfl_xor(S0, 32, 64);
        #pragma unroll
        for (int q = 0; q < 8; ++q) {
            f32x2 ta, tb;
            ta.x = __shfl_xor(Svp[q].x, 32, 64);
            ta.y = __shfl_xor(Svp[q].y, 32, 64);
            tb.x = __shfl_xor(Sv2p[q].x, 32, 64);
            tb.y = __shfl_xor(Sv2p[q].y, 32, 64);
            Svp[q] += ta;
            Sv2p[q] += tb;
        }
        if ((kc & 1) == 0) {
            float* row = &scr[((kc >> 1)*32 + o)*33];
            #pragma unroll
            for (int q = 0; q < 8; ++q) {
                row[2*q]      = Svp[q].x;  row[2*q + 1]      = Svp[q].y;
                row[16 + 2*q] = Sv2p[q].x; row[16 + 2*q + 1] = Sv2p[q].y;
            }
            row[32] = S0;
        }
        __syncthreads();

        // ---- reduce 8 groups + stats; thread t handles (oo, pp) ----
        {
            float sm = 0.f, s2 = 0.f, rs = 0.f;
            #pragma unroll
            for (int q = 0; q < 8; ++q) {
                const int b0 = (q*32 + oo)*33;
                sm += scr[b0 + pp];
                s2 += scr[b0 + 16 + pp];
                rs += scr[b0 + 32];
            }
            const float inv = 1.0f / (rs + EPSF);
            const float S1  = rs * inv;
            const float m   = sm * inv;
            float var = s2 * inv - m*m*(2.0f - S1);
            var = fmaxf(var, 0.0f) + EPSF;          // std^2 (+eps inside sqrt)
            meanS[oo*17 + pp] = m;
            i2vS [oo*17 + pp] = 0.5f / var;
            scr[oo*33 + pp] = 0.5f * __logf(var);   // log std; q=0 slot owned by this thread
        }
        __syncthreads();
        if (t < 32) {
            float lsum = 0.f;
            #pragma unroll
            for (int p = 0; p < 16; ++p) lsum += scr[t*33 + p];
            float rs = 0.f;
            #pragma unroll
            for (int q = 0; q < 8; ++q) rs += scr[(q*32 + t)*33 + 32];
            const float cost = (16.0f * bu[t] + lsum) * rs;
            const float ao   = 1.0f / (1.0f + __expf(-lam * (ba[t] - cost)));
            actS[t]  = ao;
            baseS[t] = -lsum - 8.0f*LN2PI + __logf(ao);
        }
        __syncthreads();
    }

#undef LOAD_P
#undef LOAD_W
#undef VOTES
#undef M0_BODY
#undef E_BODY

    // ---- output: [mean(512) | act(32)] per n ----
    for (int idx = t; idx < 544; idx += 512) {
        const float v = (idx < 512) ? meanS[(idx >> 4)*17 + (idx & 15)]
                                    : actS[idx - 512];
        out[n*544 + idx] = v;
    }
}

} // namespace

extern "C" void kernel_launch(void* const* d_in, const int* in_sizes, int n_in,
                              void* d_out, int out_size, void* d_ws, size_t ws_size,
                              hipStream_t stream) {
    (void)in_sizes; (void)n_in; (void)out_size; (void)d_ws; (void)ws_size;
    const float* x  = (const float*)d_in[0];
    const float* W  = (const float*)d_in[1];
    const float* bu = (const float*)d_in[2];
    const float* ba = (const float*)d_in[3];
    float* out = (float*)d_out;
    caps_em_kernel<<<dim3(392), dim3(512), 0, stream>>>(x, W, bu, ba, out);
}

// Round 8
// 130.761 us; speedup vs baseline: 1.0735x; 1.0735x over previous
//
#include <hip/hip_runtime.h>

// ConvCaps EM-routing, MI355X. 392 independent problems, one 512-thread block each.
// Thread = (o = t&31 out-cap, kc = t>>5 of 16 k-chunks, 18 k each).
//
// REGISTER UNLOCK: __launch_bounds__(512, 2).
// Measured decode of the allocator across rounds: (512,4) -> 64 VGPR budget,
// (1024,8) -> 32. Both fit: effective min waves/EU = block_waves * arg / 4,
// i.e. hipcc treats the 2nd arg as min WORKGROUPS/CU. (512,4) was demanding
// 4 blocks/CU = 8 waves/EU -> 64-VGPR cap -> every ILP attempt spilled
// (FETCH 23-675 MB). LDS (58 KB) only permits 2 blocks/CU anyway, so
// (512,2) = 4 waves/EU = 128-VGPR budget at IDENTICAL occupancy.
//
// Structure = round-4 (80.4 us, no spill at 64 VGPR): pk-fp32 votes/sacc/accum,
// DPP+swizzle softmax reduces. Carried from round 5: per-k redmax replaced by
// iteration-constant shift Mb = max_o(base) (softmax shift-invariant;
// lnp <= base <= Mb so exp never overflows).
// Fused E+M: votes recomputed 3x (M0, E0+M1, E1+M2) using unnormalized
// moments  mean = S(uv)/(rs+eps), var = S(uv^2)/(rs+eps) - m^2(2-S1),
// u_k = softmax_o(ln_ap)*c_k, c_k = a/(a+eps). r-matrix never materialized.

namespace {

constexpr int NKK = 288;
constexpr float EPSF = 1e-8f;
constexpr float LN2PI = 1.8378770664093453f;

typedef float f32x2 __attribute__((ext_vector_type(2)));

__device__ __forceinline__ float fastrcp(float x) { return __builtin_amdgcn_rcpf(x); }
__device__ __forceinline__ f32x2 splat2(float x) { f32x2 r; r.x = x; r.y = x; return r; }
__device__ __forceinline__ f32x2 fma2(f32x2 a, f32x2 b, f32x2 c) {
    return __builtin_elementwise_fma(a, b, c);
}

// DPP lane permute (VALU pipe). CTRL: 0xB1=quad_perm xor1, 0x4E=quad_perm xor2,
// 0x141=row_half_mirror (xor7), 0x140=row_mirror (xor15).
template <int CTRL>
__device__ __forceinline__ float dppf(float x) {
    return __int_as_float(__builtin_amdgcn_update_dpp(
        __float_as_int(x), __float_as_int(x), CTRL, 0xF, 0xF, false));
}
// ds_swizzle xor16 within each 32-lane group (bitmode: xor=16, and=0x1F).
__device__ __forceinline__ float swz16(float x) {
    return __int_as_float(__builtin_amdgcn_ds_swizzle(__float_as_int(x), 0x401F));
}

// Reduce over the 32-lane group (lanes 0-31 / 32-63 independently).
// XOR-mask basis {1,2,7,15,16} spans bits 0..4 -> valid butterfly.
__device__ __forceinline__ float redmax32(float v) {
    v = fmaxf(v, dppf<0xB1>(v));
    v = fmaxf(v, dppf<0x4E>(v));
    v = fmaxf(v, dppf<0x141>(v));
    v = fmaxf(v, dppf<0x140>(v));
    v = fmaxf(v, swz16(v));
    return v;
}
__device__ __forceinline__ float redsum32(float v) {
    v += dppf<0xB1>(v);
    v += dppf<0x4E>(v);
    v += dppf<0x141>(v);
    v += dppf<0x140>(v);
    v += swz16(v);
    return v;
}

__global__ __launch_bounds__(512, 2)
void caps_em_kernel(const float* __restrict__ x,
                    const float* __restrict__ Wg,
                    const float* __restrict__ bu,
                    const float* __restrict__ ba,
                    float* __restrict__ out)
{
    // LDS: 18432 + 1152 + 33792 + 2176 + 2176 + 256 = 57984 B -> 2 blocks/CU
    __shared__ float p4[NKK * 16];       // pose fragments [k*16+p]
    __shared__ float cIn[NKK];           // a/(a+eps)
    __shared__ float scr[8 * 32 * 33];   // [g][o][ Sv(16) | Sv2(16) | S0 ]
    __shared__ float meanS[32 * 17];     // mean[o*17+p]  (stride 17: conflict-free)
    __shared__ float i2vS[32 * 17];      // 1/(2*std^2)
    __shared__ float actS[32];
    __shared__ float baseS[32];          // log(act) - sum_p log std - 8*ln2pi

    const int n = blockIdx.x;
    const int t = threadIdx.x;

    // ---- gather poses: flat view of tiled (B,kh,kw,oh,ow,512) ----
    for (int idx = t; idx < NKK * 16; idx += 512) {
        unsigned g = (unsigned)n * 4608u + (unsigned)idx;
        unsigned c = g & 511u, rest = g >> 9;
        unsigned ow = rest % 7u; rest /= 7u;
        unsigned oh = rest % 7u; rest /= 7u;
        unsigned kw = rest % 3u; rest /= 3u;
        unsigned kh = rest % 3u;
        unsigned b  = rest / 3u;
        p4[idx] = x[((b*16u + 2u*oh + kh)*16u + 2u*ow + kw)*544u + c];
    }
    // ---- gather acts -> c_k ----
    for (int idx = t; idx < NKK; idx += 512) {
        unsigned g = (unsigned)n * 288u + (unsigned)idx;
        unsigned c = g & 31u, rest = g >> 5;
        unsigned ow = rest % 7u; rest /= 7u;
        unsigned oh = rest % 7u; rest /= 7u;
        unsigned kw = rest % 3u; rest /= 3u;
        unsigned kh = rest % 3u;
        unsigned b  = rest / 3u;
        const float a = x[((b*16u + 2u*oh + kh)*16u + 2u*ow + kw)*544u + 512u + c];
        cIn[idx] = a / (a + EPSF);
    }
    __syncthreads();

    const int o  = t & 31;    // out-cap (== lane&31)
    const int kc = t >> 5;    // k-chunk 0..15 (18 k each)
    const int oo = t >> 4;    // reducer row 0..31
    const int pp = t & 15;    // reducer col 0..15

    float lam = 1.0e-3f;

    for (int it = 0; it < 3; ++it) {
        lam += 1.0e-4f;

        float S0 = 0.f;
        f32x2 Svp[8], Sv2p[8];
        #pragma unroll
        for (int q = 0; q < 8; ++q) { Svp[q] = splat2(0.f); Sv2p[q] = splat2(0.f); }

        if (it == 0) {
            // ---- M0: uniform r -> u_k = c_k/32 (same for all o) ----
            #pragma unroll 2
            for (int kk = 0; kk < 18; ++kk) {
                const int k = kc*18 + kk;
                const float w = cIn[k] * 0.03125f;
                const f32x2 w2 = splat2(w);
                float P[16]; f32x2 Wl2[8];
                #pragma unroll
                for (int j = 0; j < 4; ++j) {
                    const float4 v4 = *(const float4*)&p4[k*16 + 4*j];
                    P[4*j] = v4.x; P[4*j+1] = v4.y; P[4*j+2] = v4.z; P[4*j+3] = v4.w;
                    const float4 w4 = *(const float4*)&Wg[(k*32 + o)*16 + 4*j];
                    f32x2 lo; lo.x = w4.x; lo.y = w4.y;
                    f32x2 hi; hi.x = w4.z; hi.y = w4.w;
                    Wl2[2*j] = lo; Wl2[2*j+1] = hi;
                }
                S0 += w;
                #pragma unroll
                for (int i = 0; i < 4; ++i) {
                    #pragma unroll
                    for (int h = 0; h < 2; ++h) {
                        const int q = i*2 + h;
                        f32x2 acc = splat2(P[i*4]) * Wl2[h];
                        acc = fma2(splat2(P[i*4+1]), Wl2[2+h], acc);
                        acc = fma2(splat2(P[i*4+2]), Wl2[4+h], acc);
                        acc = fma2(splat2(P[i*4+3]), Wl2[6+h], acc);
                        const f32x2 wv = w2 * acc;
                        Svp[q] += wv;
                        Sv2p[q] = fma2(wv, acc, Sv2p[q]);
                    }
                }
            }
        } else {
            // ---- fused E(prev stats) + M accumulate, packed fp32 ----
            f32x2 M2[8], I2[8];
            #pragma unroll
            for (int q = 0; q < 8; ++q) {
                f32x2 m; m.x = meanS[o*17 + 2*q]; m.y = meanS[o*17 + 2*q + 1];
                f32x2 iv; iv.x = i2vS[o*17 + 2*q]; iv.y = i2vS[o*17 + 2*q + 1];
                M2[q] = m; I2[q] = iv;
            }
            const float base = baseS[o];
            const float Mb = redmax32(base);   // iteration-constant softmax shift
            for (int kk = 0; kk < 18; ++kk) {
                const int k = kc*18 + kk;
                float P[16]; f32x2 Wl2[8];
                #pragma unroll
                for (int j = 0; j < 4; ++j) {
                    const float4 v4 = *(const float4*)&p4[k*16 + 4*j];
                    P[4*j] = v4.x; P[4*j+1] = v4.y; P[4*j+2] = v4.z; P[4*j+3] = v4.w;
                    const float4 w4 = *(const float4*)&Wg[(k*32 + o)*16 + 4*j];
                    f32x2 lo; lo.x = w4.x; lo.y = w4.y;
                    f32x2 hi; hi.x = w4.z; hi.y = w4.w;
                    Wl2[2*j] = lo; Wl2[2*j+1] = hi;
                }
                f32x2 v2[8];
                f32x2 sa[4];
                #pragma unroll
                for (int i = 0; i < 4; ++i) {
                    sa[i] = splat2(0.f);
                    #pragma unroll
                    for (int h = 0; h < 2; ++h) {
                        const int q = i*2 + h;
                        f32x2 acc = splat2(P[i*4]) * Wl2[h];
                        acc = fma2(splat2(P[i*4+1]), Wl2[2+h], acc);
                        acc = fma2(splat2(P[i*4+2]), Wl2[4+h], acc);
                        acc = fma2(splat2(P[i*4+3]), Wl2[6+h], acc);
                        v2[q] = acc;
                        const f32x2 d = acc - M2[q];
                        sa[i] = fma2(d * d, I2[q], sa[i]);
                    }
                }
                const f32x2 sv = (sa[0] + sa[1]) + (sa[2] + sa[3]);
                const float lnp = base - (sv.x + sv.y);
                const float e  = __expf(lnp - Mb);
                const float ss = redsum32(e);
                const float u = e * fastrcp(ss) * cIn[k];
                S0 += u;
                const f32x2 u2 = splat2(u);
                #pragma unroll
                for (int q = 0; q < 8; ++q) {
                    const f32x2 uv = u2 * v2[q];
                    Svp[q] += uv;
                    Sv2p[q] = fma2(uv, v2[q], Sv2p[q]);
                }
            }
        }

        // ---- combine kc pairs (partner lane^32, same wave) -> 8 groups ----
        S0 += __shfl_xor(S0, 32, 64);
        #pragma unroll
        for (int q = 0; q < 8; ++q) {
            f32x2 ta, tb;
            ta.x = __shfl_xor(Svp[q].x, 32, 64);
            ta.y = __shfl_xor(Svp[q].y, 32, 64);
            tb.x = __shfl_xor(Sv2p[q].x, 32, 64);
            tb.y = __shfl_xor(Sv2p[q].y, 32, 64);
            Svp[q] += ta;
            Sv2p[q] += tb;
        }
        if ((kc & 1) == 0) {
            float* row = &scr[((kc >> 1)*32 + o)*33];
            #pragma unroll
            for (int q = 0; q < 8; ++q) {
                row[2*q]      = Svp[q].x;  row[2*q + 1]      = Svp[q].y;
                row[16 + 2*q] = Sv2p[q].x; row[16 + 2*q + 1] = Sv2p[q].y;
            }
            row[32] = S0;
        }
        __syncthreads();

        // ---- reduce 8 groups + stats; thread t handles (oo, pp) ----
        {
            float sm = 0.f, s2 = 0.f, rs = 0.f;
            #pragma unroll
            for (int q = 0; q < 8; ++q) {
                const int b0 = (q*32 + oo)*33;
                sm += scr[b0 + pp];
                s2 += scr[b0 + 16 + pp];
                rs += scr[b0 + 32];
            }
            const float inv = 1.0f / (rs + EPSF);
            const float S1  = rs * inv;
            const float m   = sm * inv;
            float var = s2 * inv - m*m*(2.0f - S1);
            var = fmaxf(var, 0.0f) + EPSF;          // std^2 (+eps inside sqrt)
            meanS[oo*17 + pp] = m;
            i2vS [oo*17 + pp] = 0.5f / var;
            scr[oo*33 + pp] = 0.5f * __logf(var);   // log std; q=0 slot owned by this thread
        }
        __syncthreads();
        if (t < 32) {
            float lsum = 0.f;
            #pragma unroll
            for (int p = 0; p < 16; ++p) lsum += scr[t*33 + p];
            float rs = 0.f;
            #pragma unroll
            for (int q = 0; q < 8; ++q) rs += scr[(q*32 + t)*33 + 32];
            const float cost = (16.0f * bu[t] + lsum) * rs;
            const float ao   = 1.0f / (1.0f + __expf(-lam * (ba[t] - cost)));
            actS[t]  = ao;
            baseS[t] = -lsum - 8.0f*LN2PI + __logf(ao);
        }
        __syncthreads();
    }

    // ---- output: [mean(512) | act(32)] per n ----
    for (int idx = t; idx < 544; idx += 512) {
        const float v = (idx < 512) ? meanS[(idx >> 4)*17 + (idx & 15)]
                                    : actS[idx - 512];
        out[n*544 + idx] = v;
    }
}

} // namespace

extern "C" void kernel_launch(void* const* d_in, const int* in_sizes, int n_in,
                              void* d_out, int out_size, void* d_ws, size_t ws_size,
                              hipStream_t stream) {
    (void)in_sizes; (void)n_in; (void)out_size; (void)d_ws; (void)ws_size;
    const float* x  = (const float*)d_in[0];
    const float* W  = (const float*)d_in[1];
    const float* bu = (const float*)d_in[2];
    const float* ba = (const float*)d_in[3];
    float* out = (float*)d_out;
    caps_em_kernel<<<dim3(392), dim3(512), 0, stream>>>(x, W, bu, ba, out);
}

// Round 9
// 126.788 us; speedup vs baseline: 1.1072x; 1.0313x over previous
//
#include <hip/hip_runtime.h>

// ConvCaps EM-routing, MI355X. 392 independent problems, one 512-thread block each.
// Thread = (o = t&31 out-cap, kc = t>>5 of 16 k-chunks, 18 k each).
//
// __launch_bounds__(512, 2): measured VGPR budget unlock (round 8: VGPR 64->80,
// no spill). hipcc treats the 2nd arg as min WORKGROUPS/CU; (512,4) demanded
// 8 waves/EU -> 64-VGPR cap -> every earlier ILP attempt spilled. LDS (58 KB)
// permits only 2 blocks/CU anyway, so (512,2) = 4 waves/EU = ~128-VGPR budget
// at identical occupancy.
//
// Kernel is latency-chain-bound per k (time flat 80-84 us across large
// instruction-count changes; VALUBusy 37-45%; grid-capped ~4 waves/SIMD).
// This version software-pipelines BOTH operand streams one k ahead: P (LDS,
// ~120 cy) and W (L2, ~200-400 cy) die right after the votes, so the body is
// votes(cur) -> issue next P+W loads -> sacc/softmax/accumulate (loads'
// latency hides under ~150+ issue cycles). Double-buffered raw float4 regs;
// unpack at use so waitcnts land at next body's votes.
//
// Math: fused E+M, votes recomputed 3x (M0, E0+M1, E1+M2); unnormalized
// moments  mean = S(uv)/(rs+eps), var = S(uv^2)/(rs+eps) - m^2(2-S1);
// u_k = softmax_o(ln_ap)*c_k, c_k = a/(a+eps); r-matrix never materialized.
// Per-k redmax replaced by iteration-constant shift Mb = max_o(base)
// (softmax shift-invariant; lnp <= base <= Mb so exp never overflows).
// Packed fp32 (v_pk_*) vote/sacc/accum; DPP+swizzle 32-lane reduces.

namespace {

constexpr int NKK = 288;
constexpr float EPSF = 1e-8f;
constexpr float LN2PI = 1.8378770664093453f;

typedef float f32x2 __attribute__((ext_vector_type(2)));

__device__ __forceinline__ float fastrcp(float x) { return __builtin_amdgcn_rcpf(x); }
__device__ __forceinline__ f32x2 splat2(float x) { f32x2 r; r.x = x; r.y = x; return r; }
__device__ __forceinline__ f32x2 fma2(f32x2 a, f32x2 b, f32x2 c) {
    return __builtin_elementwise_fma(a, b, c);
}
__device__ __forceinline__ f32x2 lo2(float4 v) { f32x2 r; r.x = v.x; r.y = v.y; return r; }
__device__ __forceinline__ f32x2 hi2(float4 v) { f32x2 r; r.x = v.z; r.y = v.w; return r; }

// DPP lane permute (VALU pipe). CTRL: 0xB1=quad_perm xor1, 0x4E=quad_perm xor2,
// 0x141=row_half_mirror (xor7), 0x140=row_mirror (xor15).
template <int CTRL>
__device__ __forceinline__ float dppf(float x) {
    return __int_as_float(__builtin_amdgcn_update_dpp(
        __float_as_int(x), __float_as_int(x), CTRL, 0xF, 0xF, false));
}
// ds_swizzle xor16 within each 32-lane group (bitmode: xor=16, and=0x1F).
__device__ __forceinline__ float swz16(float x) {
    return __int_as_float(__builtin_amdgcn_ds_swizzle(__float_as_int(x), 0x401F));
}

// Reduce over the 32-lane group (lanes 0-31 / 32-63 independently).
// XOR-mask basis {1,2,7,15,16} spans bits 0..4 -> valid butterfly.
__device__ __forceinline__ float redmax32(float v) {
    v = fmaxf(v, dppf<0xB1>(v));
    v = fmaxf(v, dppf<0x4E>(v));
    v = fmaxf(v, dppf<0x141>(v));
    v = fmaxf(v, dppf<0x140>(v));
    v = fmaxf(v, swz16(v));
    return v;
}
__device__ __forceinline__ float redsum32(float v) {
    v += dppf<0xB1>(v);
    v += dppf<0x4E>(v);
    v += dppf<0x141>(v);
    v += dppf<0x140>(v);
    v += swz16(v);
    return v;
}

__global__ __launch_bounds__(512, 2)
void caps_em_kernel(const float* __restrict__ x,
                    const float* __restrict__ Wg,
                    const float* __restrict__ bu,
                    const float* __restrict__ ba,
                    float* __restrict__ out)
{
    // LDS: 18432 + 1152 + 33792 + 2176 + 2176 + 256 = 57984 B -> 2 blocks/CU
    __shared__ float p4[NKK * 16];       // pose fragments [k*16+p]
    __shared__ float cIn[NKK];           // a/(a+eps)
    __shared__ float scr[8 * 32 * 33];   // [g][o][ Sv(16) | Sv2(16) | S0 ]
    __shared__ float meanS[32 * 17];     // mean[o*17+p]  (stride 17: conflict-free)
    __shared__ float i2vS[32 * 17];      // 1/(2*std^2)
    __shared__ float actS[32];
    __shared__ float baseS[32];          // log(act) - sum_p log std - 8*ln2pi

    const int n = blockIdx.x;
    const int t = threadIdx.x;

    // ---- gather poses: flat view of tiled (B,kh,kw,oh,ow,512) ----
    for (int idx = t; idx < NKK * 16; idx += 512) {
        unsigned g = (unsigned)n * 4608u + (unsigned)idx;
        unsigned c = g & 511u, rest = g >> 9;
        unsigned ow = rest % 7u; rest /= 7u;
        unsigned oh = rest % 7u; rest /= 7u;
        unsigned kw = rest % 3u; rest /= 3u;
        unsigned kh = rest % 3u;
        unsigned b  = rest / 3u;
        p4[idx] = x[((b*16u + 2u*oh + kh)*16u + 2u*ow + kw)*544u + c];
    }
    // ---- gather acts -> c_k ----
    for (int idx = t; idx < NKK; idx += 512) {
        unsigned g = (unsigned)n * 288u + (unsigned)idx;
        unsigned c = g & 31u, rest = g >> 5;
        unsigned ow = rest % 7u; rest /= 7u;
        unsigned oh = rest % 7u; rest /= 7u;
        unsigned kw = rest % 3u; rest /= 3u;
        unsigned kh = rest % 3u;
        unsigned b  = rest / 3u;
        const float a = x[((b*16u + 2u*oh + kh)*16u + 2u*ow + kw)*544u + 512u + c];
        cIn[idx] = a / (a + EPSF);
    }
    __syncthreads();

    const int o  = t & 31;    // out-cap (== lane&31)
    const int kc = t >> 5;    // k-chunk 0..15 (18 k each)
    const int oo = t >> 4;    // reducer row 0..31
    const int pp = t & 15;    // reducer col 0..15

    float lam = 1.0e-3f;

// Prefetch W row for K_ into raw float4 regs (no unpack -> no waitcnt here).
#define LOAD_W(WD, K_)                                                     \
    {                                                                      \
        const float4* wp_ = (const float4*)&Wg[((K_)*32 + o)*16];          \
        WD[0] = wp_[0]; WD[1] = wp_[1]; WD[2] = wp_[2]; WD[3] = wp_[3];    \
    }
// Prefetch P row (LDS broadcast) for K_ into raw float4 regs.
#define LOAD_P(PD, K_)                                                     \
    {                                                                      \
        const float4* pp_ = (const float4*)&p4[(K_)*16];                   \
        PD[0] = pp_[0]; PD[1] = pp_[1]; PD[2] = pp_[2]; PD[3] = pp_[3];    \
    }

// Votes from PC x WC (unpack at use). V2[q], q = i*2+h.
#define VOTES(PC, WC, V2)                                                  \
    _Pragma("unroll")                                                      \
    for (int i = 0; i < 4; ++i) {                                          \
        _Pragma("unroll")                                                  \
        for (int h = 0; h < 2; ++h) {                                      \
            const f32x2 w0 = (h == 0) ? lo2(WC[0]) : hi2(WC[0]);           \
            const f32x2 w1 = (h == 0) ? lo2(WC[1]) : hi2(WC[1]);           \
            const f32x2 w2 = (h == 0) ? lo2(WC[2]) : hi2(WC[2]);           \
            const f32x2 w3 = (h == 0) ? lo2(WC[3]) : hi2(WC[3]);           \
            f32x2 acc = splat2(PC[i].x) * w0;                              \
            acc = fma2(splat2(PC[i].y), w1, acc);                          \
            acc = fma2(splat2(PC[i].z), w2, acc);                          \
            acc = fma2(splat2(PC[i].w), w3, acc);                          \
            V2[i*2 + h] = acc;                                             \
        }                                                                  \
    }

// M0 body: uniform r. Consumes PC/WC, prefetches KN_ into PN/WN.
#define M0_BODY(K_, PC, WC, KN_, PN, WN)                                   \
    {                                                                      \
        const float cI_ = cIn[(K_)];                                       \
        f32x2 v2[8];                                                       \
        VOTES(PC, WC, v2)                                                  \
        LOAD_P(PN, (KN_))                                                  \
        LOAD_W(WN, (KN_))                                                  \
        const float w_ = cI_ * 0.03125f;                                   \
        const f32x2 w2_ = splat2(w_);                                      \
        S0 += w_;                                                          \
        _Pragma("unroll")                                                  \
        for (int q = 0; q < 8; ++q) {                                      \
            const f32x2 wv = w2_ * v2[q];                                  \
            Svp[q] += wv;                                                  \
            Sv2p[q] = fma2(wv, v2[q], Sv2p[q]);                            \
        }                                                                  \
    }

// E body: fused E(prev stats)+M accumulate. Consumes PC/WC, prefetches KN_.
#define E_BODY(K_, PC, WC, KN_, PN, WN)                                    \
    {                                                                      \
        const float cI_ = cIn[(K_)];                                       \
        f32x2 v2[8];                                                       \
        VOTES(PC, WC, v2)                                                  \
        LOAD_P(PN, (KN_))                                                  \
        LOAD_W(WN, (KN_))                                                  \
        f32x2 sa0 = splat2(0.f), sa1 = splat2(0.f);                        \
        _Pragma("unroll")                                                  \
        for (int q = 0; q < 8; ++q) {                                      \
            const f32x2 d = v2[q] - M2[q];                                 \
            if (q & 1) sa1 = fma2(d * d, I2[q], sa1);                      \
            else       sa0 = fma2(d * d, I2[q], sa0);                      \
        }                                                                  \
        const f32x2 sv = sa0 + sa1;                                        \
        const float lnp = base - (sv.x + sv.y);                            \
        const float e  = __expf(lnp - Mb);                                 \
        const float ss = redsum32(e);                                      \
        const float u = e * fastrcp(ss) * cI_;                             \
        S0 += u;                                                           \
        const f32x2 u2 = splat2(u);                                        \
        _Pragma("unroll")                                                  \
        for (int q = 0; q < 8; ++q) {                                      \
            const f32x2 uv = u2 * v2[q];                                   \
            Svp[q] += uv;                                                  \
            Sv2p[q] = fma2(uv, v2[q], Sv2p[q]);                            \
        }                                                                  \
    }

    for (int it = 0; it < 3; ++it) {
        lam += 1.0e-4f;

        float S0 = 0.f;
        f32x2 Svp[8], Sv2p[8];
        #pragma unroll
        for (int q = 0; q < 8; ++q) { Svp[q] = splat2(0.f); Sv2p[q] = splat2(0.f); }

        const int k0 = kc * 18;
        float4 Pa[4], Pb[4], Wa[4], Wb[4];
        LOAD_P(Pa, k0)
        LOAD_W(Wa, k0)

        if (it == 0) {
            // ---- M0: uniform r -> u_k = c_k/32 (same for all o) ----
            #pragma unroll 1
            for (int kk = 0; kk < 18; kk += 2) {
                const int k = k0 + kk;
                M0_BODY(k, Pa, Wa, k + 1, Pb, Wb)
                const int kn2 = (kk == 16) ? k0 : k + 2;
                M0_BODY(k + 1, Pb, Wb, kn2, Pa, Wa)
            }
        } else {
            // ---- fused E(prev stats) + M accumulate, dual P+W pipeline ----
            f32x2 M2[8], I2[8];
            #pragma unroll
            for (int q = 0; q < 8; ++q) {
                f32x2 m; m.x = meanS[o*17 + 2*q]; m.y = meanS[o*17 + 2*q + 1];
                f32x2 iv; iv.x = i2vS[o*17 + 2*q]; iv.y = i2vS[o*17 + 2*q + 1];
                M2[q] = m; I2[q] = iv;
            }
            const float base = baseS[o];
            const float Mb = redmax32(base);   // iteration-constant softmax shift
            #pragma unroll 1
            for (int kk = 0; kk < 18; kk += 2) {
                const int k = k0 + kk;
                E_BODY(k, Pa, Wa, k + 1, Pb, Wb)
                const int kn2 = (kk == 16) ? k0 : k + 2;
                E_BODY(k + 1, Pb, Wb, kn2, Pa, Wa)
            }
        }

        // ---- combine kc pairs (partner lane^32, same wave) -> 8 groups ----
        S0 += __shfl_xor(S0, 32, 64);
        #pragma unroll
        for (int q = 0; q < 8; ++q) {
            f32x2 ta, tb;
            ta.x = __shfl_xor(Svp[q].x, 32, 64);
            ta.y = __shfl_xor(Svp[q].y, 32, 64);
            tb.x = __shfl_xor(Sv2p[q].x, 32, 64);
            tb.y = __shfl_xor(Sv2p[q].y, 32, 64);
            Svp[q] += ta;
            Sv2p[q] += tb;
        }
        if ((kc & 1) == 0) {
            float* row = &scr[((kc >> 1)*32 + o)*33];
            #pragma unroll
            for (int q = 0; q < 8; ++q) {
                row[2*q]      = Svp[q].x;  row[2*q + 1]      = Svp[q].y;
                row[16 + 2*q] = Sv2p[q].x; row[16 + 2*q + 1] = Sv2p[q].y;
            }
            row[32] = S0;
        }
        __syncthreads();

        // ---- reduce 8 groups + stats; thread t handles (oo, pp) ----
        {
            float sm = 0.f, s2 = 0.f, rs = 0.f;
            #pragma unroll
            for (int q = 0; q < 8; ++q) {
                const int b0 = (q*32 + oo)*33;
                sm += scr[b0 + pp];
                s2 += scr[b0 + 16 + pp];
                rs += scr[b0 + 32];
            }
            const float inv = 1.0f / (rs + EPSF);
            const float S1  = rs * inv;
            const float m   = sm * inv;
            float var = s2 * inv - m*m*(2.0f - S1);
            var = fmaxf(var, 0.0f) + EPSF;          // std^2 (+eps inside sqrt)
            meanS[oo*17 + pp] = m;
            i2vS [oo*17 + pp] = 0.5f / var;
            scr[oo*33 + pp] = 0.5f * __logf(var);   // log std; q=0 slot owned by this thread
        }
        __syncthreads();
        if (t < 32) {
            float lsum = 0.f;
            #pragma unroll
            for (int p = 0; p < 16; ++p) lsum += scr[t*33 + p];
            float rs = 0.f;
            #pragma unroll
            for (int q = 0; q < 8; ++q) rs += scr[(q*32 + t)*33 + 32];
            const float cost = (16.0f * bu[t] + lsum) * rs;
            const float ao   = 1.0f / (1.0f + __expf(-lam * (ba[t] - cost)));
            actS[t]  = ao;
            baseS[t] = -lsum - 8.0f*LN2PI + __logf(ao);
        }
        __syncthreads();
    }

#undef LOAD_P
#undef LOAD_W
#undef VOTES
#undef M0_BODY
#undef E_BODY

    // ---- output: [mean(512) | act(32)] per n ----
    for (int idx = t; idx < 544; idx += 512) {
        const float v = (idx < 512) ? meanS[(idx >> 4)*17 + (idx & 15)]
                                    : actS[idx - 512];
        out[n*544 + idx] = v;
    }
}

} // namespace

extern "C" void kernel_launch(void* const* d_in, const int* in_sizes, int n_in,
                              void* d_out, int out_size, void* d_ws, size_t ws_size,
                              hipStream_t stream) {
    (void)in_sizes; (void)n_in; (void)out_size; (void)d_ws; (void)ws_size;
    const float* x  = (const float*)d_in[0];
    const float* W  = (const float*)d_in[1];
    const float* bu = (const float*)d_in[2];
    const float* ba = (const float*)d_in[3];
    float* out = (float*)d_out;
    caps_em_kernel<<<dim3(392), dim3(512), 0, stream>>>(x, W, bu, ba, out);
}

// Round 10
// 123.924 us; speedup vs baseline: 1.1328x; 1.0231x over previous
//
#include <hip/hip_runtime.h>

// ConvCaps EM-routing, MI355X. 392 independent problems, one 512-thread block each.
// Thread = (o = t&31 out-cap, kc = t>>5 of 16 k-chunks, 18 k each).
//
// ROUND-10 KEY CHANGE: W layout transpose (one-shot prep kernel into d_ws).
// Diagnosis: time pinned at 80-84us across 6 structurally different variants
// (scalar/pk/DPP/prefetch, 64-120 VGPR, no spill) with VALUBusy 37-45% ->
// a per-CU pipe saturated identically by all variants. The W loads are it:
// lane o reads float4 at (k*32+o)*16 floats = 16-B accesses at 64-B stride.
// Each of 4 load instrs touches 64 distinct cache lines/wave (1/4 line used),
// re-touching the same lines 4x => ~256 line-transactions/body/wave through
// the CU's single TA (~1 line/cy) => ~220k cy/CU, matching measured wall.
// Transposed layout Wt[k][j][o][4]: quarter-j load is lane-contiguous 512 B
// per half-wave => 16 lines/instr, 64/body (4x cut in the saturated pipe).
//
// __launch_bounds__(512,2): measured VGPR unlock (2nd arg acts as min
// WORKGROUPS/CU; (512,4) capped at 64 VGPR and spilled all ILP attempts).
// LDS 58KB -> 2 blocks/CU either way.
//
// Math: fused E+M, votes recomputed 3x (M0, E0+M1, E1+M2); unnormalized
// moments  mean = S(uv)/(rs+eps), var = S(uv^2)/(rs+eps) - m^2(2-S1);
// u_k = softmax_o(ln_ap)*c_k, c_k = a/(a+eps); r never materialized.
// Iteration-constant softmax shift Mb = max_o(base). Packed fp32 vote/sacc/
// accum; DPP+swizzle 32-lane reduces; P+W double-buffered one k ahead.

namespace {

constexpr int NKK = 288;
constexpr float EPSF = 1e-8f;
constexpr float LN2PI = 1.8378770664093453f;

typedef float f32x2 __attribute__((ext_vector_type(2)));

__device__ __forceinline__ float fastrcp(float x) { return __builtin_amdgcn_rcpf(x); }
__device__ __forceinline__ f32x2 splat2(float x) { f32x2 r; r.x = x; r.y = x; return r; }
__device__ __forceinline__ f32x2 fma2(f32x2 a, f32x2 b, f32x2 c) {
    return __builtin_elementwise_fma(a, b, c);
}
__device__ __forceinline__ f32x2 lo2(float4 v) { f32x2 r; r.x = v.x; r.y = v.y; return r; }
__device__ __forceinline__ f32x2 hi2(float4 v) { f32x2 r; r.x = v.z; r.y = v.w; return r; }

template <int CTRL>
__device__ __forceinline__ float dppf(float x) {
    return __int_as_float(__builtin_amdgcn_update_dpp(
        __float_as_int(x), __float_as_int(x), CTRL, 0xF, 0xF, false));
}
__device__ __forceinline__ float swz16(float x) {
    return __int_as_float(__builtin_amdgcn_ds_swizzle(__float_as_int(x), 0x401F));
}

__device__ __forceinline__ float redmax32(float v) {
    v = fmaxf(v, dppf<0xB1>(v));
    v = fmaxf(v, dppf<0x4E>(v));
    v = fmaxf(v, dppf<0x141>(v));
    v = fmaxf(v, dppf<0x140>(v));
    v = fmaxf(v, swz16(v));
    return v;
}
__device__ __forceinline__ float redsum32(float v) {
    v += dppf<0xB1>(v);
    v += dppf<0x4E>(v);
    v += dppf<0x141>(v);
    v += dppf<0x140>(v);
    v += swz16(v);
    return v;
}

// W row loader. TR: Wt[k][j][o][4] (lane-contiguous per quarter).
// non-TR fallback: original Wg[(k*32+o)*16].
template <bool TR>
__device__ __forceinline__ void load_w(float4* WD, const float* __restrict__ Wg,
                                       const float4* __restrict__ Wt4, int k, int o) {
    if constexpr (TR) {
        const float4* wp = Wt4 + (size_t)(k * 4) * 32 + o;
        WD[0] = wp[0]; WD[1] = wp[32]; WD[2] = wp[64]; WD[3] = wp[96];
    } else {
        const float4* wp = (const float4*)&Wg[(k * 32 + o) * 16];
        WD[0] = wp[0]; WD[1] = wp[1]; WD[2] = wp[2]; WD[3] = wp[3];
    }
}

// Prep: Wg[k][o][p16] -> Wt[k][j4][o][4f].  36864 float4 moves.
__global__ __launch_bounds__(256)
void transpose_w(const float* __restrict__ Wg, float* __restrict__ Wt) {
    const int idx = blockIdx.x * 256 + threadIdx.x;   // grid = 144 blocks exactly
    const int j = idx & 3;
    const int o = (idx >> 2) & 31;
    const int k = idx >> 7;
    const float4 v = ((const float4*)Wg)[idx];
    ((float4*)Wt)[((k * 4 + j) * 32 + o)] = v;
}

template <bool TR>
__global__ __launch_bounds__(512, 2)
void caps_em_kernel(const float* __restrict__ x,
                    const float* __restrict__ Wg,
                    const float4* __restrict__ Wt4,
                    const float* __restrict__ bu,
                    const float* __restrict__ ba,
                    float* __restrict__ out)
{
    // LDS: 18432 + 1152 + 33792 + 2176 + 2176 + 256 = 57984 B -> 2 blocks/CU
    __shared__ float p4[NKK * 16];       // pose fragments [k*16+p]
    __shared__ float cIn[NKK];           // a/(a+eps)
    __shared__ float scr[8 * 32 * 33];   // [g][o][ Sv(16) | Sv2(16) | S0 ]
    __shared__ float meanS[32 * 17];     // mean[o*17+p]  (stride 17: conflict-free)
    __shared__ float i2vS[32 * 17];      // 1/(2*std^2)
    __shared__ float actS[32];
    __shared__ float baseS[32];          // log(act) - sum_p log std - 8*ln2pi

    const int n = blockIdx.x;
    const int t = threadIdx.x;

    // ---- gather poses: flat view of tiled (B,kh,kw,oh,ow,512) ----
    for (int idx = t; idx < NKK * 16; idx += 512) {
        unsigned g = (unsigned)n * 4608u + (unsigned)idx;
        unsigned c = g & 511u, rest = g >> 9;
        unsigned ow = rest % 7u; rest /= 7u;
        unsigned oh = rest % 7u; rest /= 7u;
        unsigned kw = rest % 3u; rest /= 3u;
        unsigned kh = rest % 3u;
        unsigned b  = rest / 3u;
        p4[idx] = x[((b*16u + 2u*oh + kh)*16u + 2u*ow + kw)*544u + c];
    }
    // ---- gather acts -> c_k ----
    for (int idx = t; idx < NKK; idx += 512) {
        unsigned g = (unsigned)n * 288u + (unsigned)idx;
        unsigned c = g & 31u, rest = g >> 5;
        unsigned ow = rest % 7u; rest /= 7u;
        unsigned oh = rest % 7u; rest /= 7u;
        unsigned kw = rest % 3u; rest /= 3u;
        unsigned kh = rest % 3u;
        unsigned b  = rest / 3u;
        const float a = x[((b*16u + 2u*oh + kh)*16u + 2u*ow + kw)*544u + 512u + c];
        cIn[idx] = a / (a + EPSF);
    }
    __syncthreads();

    const int o  = t & 31;    // out-cap (== lane&31)
    const int kc = t >> 5;    // k-chunk 0..15 (18 k each)
    const int oo = t >> 4;    // reducer row 0..31
    const int pp = t & 15;    // reducer col 0..15

    float lam = 1.0e-3f;

#define LOAD_P(PD, K_)                                                     \
    {                                                                      \
        const float4* pp_ = (const float4*)&p4[(K_)*16];                   \
        PD[0] = pp_[0]; PD[1] = pp_[1]; PD[2] = pp_[2]; PD[3] = pp_[3];    \
    }

#define VOTES(PC, WC, V2)                                                  \
    _Pragma("unroll")                                                      \
    for (int i = 0; i < 4; ++i) {                                          \
        _Pragma("unroll")                                                  \
        for (int h = 0; h < 2; ++h) {                                      \
            const f32x2 w0 = (h == 0) ? lo2(WC[0]) : hi2(WC[0]);           \
            const f32x2 w1 = (h == 0) ? lo2(WC[1]) : hi2(WC[1]);           \
            const f32x2 w2 = (h == 0) ? lo2(WC[2]) : hi2(WC[2]);           \
            const f32x2 w3 = (h == 0) ? lo2(WC[3]) : hi2(WC[3]);           \
            f32x2 acc = splat2(PC[i].x) * w0;                              \
            acc = fma2(splat2(PC[i].y), w1, acc);                          \
            acc = fma2(splat2(PC[i].z), w2, acc);                          \
            acc = fma2(splat2(PC[i].w), w3, acc);                          \
            V2[i*2 + h] = acc;                                             \
        }                                                                  \
    }

#define M0_BODY(K_, PC, WC, KN_, PN, WN)                                   \
    {                                                                      \
        const float cI_ = cIn[(K_)];                                       \
        f32x2 v2[8];                                                       \
        VOTES(PC, WC, v2)                                                  \
        LOAD_P(PN, (KN_))                                                  \
        load_w<TR>(WN, Wg, Wt4, (KN_), o);                                 \
        const float w_ = cI_ * 0.03125f;                                   \
        const f32x2 w2_ = splat2(w_);                                      \
        S0 += w_;                                                          \
        _Pragma("unroll")                                                  \
        for (int q = 0; q < 8; ++q) {                                      \
            const f32x2 wv = w2_ * v2[q];                                  \
            Svp[q] += wv;                                                  \
            Sv2p[q] = fma2(wv, v2[q], Sv2p[q]);                            \
        }                                                                  \
    }

#define E_BODY(K_, PC, WC, KN_, PN, WN)                                    \
    {                                                                      \
        const float cI_ = cIn[(K_)];                                       \
        f32x2 v2[8];                                                       \
        VOTES(PC, WC, v2)                                                  \
        LOAD_P(PN, (KN_))                                                  \
        load_w<TR>(WN, Wg, Wt4, (KN_), o);                                 \
        f32x2 sa0 = splat2(0.f), sa1 = splat2(0.f);                        \
        _Pragma("unroll")                                                  \
        for (int q = 0; q < 8; ++q) {                                      \
            const f32x2 d = v2[q] - M2[q];                                 \
            if (q & 1) sa1 = fma2(d * d, I2[q], sa1);                      \
            else       sa0 = fma2(d * d, I2[q], sa0);                      \
        }                                                                  \
        const f32x2 sv = sa0 + sa1;                                        \
        const float lnp = base - (sv.x + sv.y);                            \
        const float e  = __expf(lnp - Mb);                                 \
        const float ss = redsum32(e);                                      \
        const float u = e * fastrcp(ss) * cI_;                             \
        S0 += u;                                                           \
        const f32x2 u2 = splat2(u);                                        \
        _Pragma("unroll")                                                  \
        for (int q = 0; q < 8; ++q) {                                      \
            const f32x2 uv = u2 * v2[q];                                   \
            Svp[q] += uv;                                                  \
            Sv2p[q] = fma2(uv, v2[q], Sv2p[q]);                            \
        }                                                                  \
    }

    for (int it = 0; it < 3; ++it) {
        lam += 1.0e-4f;

        float S0 = 0.f;
        f32x2 Svp[8], Sv2p[8];
        #pragma unroll
        for (int q = 0; q < 8; ++q) { Svp[q] = splat2(0.f); Sv2p[q] = splat2(0.f); }

        const int k0 = kc * 18;
        float4 Pa[4], Pb[4], Wa[4], Wb[4];
        LOAD_P(Pa, k0)
        load_w<TR>(Wa, Wg, Wt4, k0, o);

        if (it == 0) {
            // ---- M0: uniform r -> u_k = c_k/32 (same for all o) ----
            #pragma unroll 1
            for (int kk = 0; kk < 18; kk += 2) {
                const int k = k0 + kk;
                M0_BODY(k, Pa, Wa, k + 1, Pb, Wb)
                const int kn2 = (kk == 16) ? k0 : k + 2;
                M0_BODY(k + 1, Pb, Wb, kn2, Pa, Wa)
            }
        } else {
            // ---- fused E(prev stats) + M accumulate, dual P+W pipeline ----
            f32x2 M2[8], I2[8];
            #pragma unroll
            for (int q = 0; q < 8; ++q) {
                f32x2 m; m.x = meanS[o*17 + 2*q]; m.y = meanS[o*17 + 2*q + 1];
                f32x2 iv; iv.x = i2vS[o*17 + 2*q]; iv.y = i2vS[o*17 + 2*q + 1];
                M2[q] = m; I2[q] = iv;
            }
            const float base = baseS[o];
            const float Mb = redmax32(base);   // iteration-constant softmax shift
            #pragma unroll 1
            for (int kk = 0; kk < 18; kk += 2) {
                const int k = k0 + kk;
                E_BODY(k, Pa, Wa, k + 1, Pb, Wb)
                const int kn2 = (kk == 16) ? k0 : k + 2;
                E_BODY(k + 1, Pb, Wb, kn2, Pa, Wa)
            }
        }

        // ---- combine kc pairs (partner lane^32, same wave) -> 8 groups ----
        S0 += __shfl_xor(S0, 32, 64);
        #pragma unroll
        for (int q = 0; q < 8; ++q) {
            f32x2 ta, tb;
            ta.x = __shfl_xor(Svp[q].x, 32, 64);
            ta.y = __shfl_xor(Svp[q].y, 32, 64);
            tb.x = __shfl_xor(Sv2p[q].x, 32, 64);
            tb.y = __shfl_xor(Sv2p[q].y, 32, 64);
            Svp[q] += ta;
            Sv2p[q] += tb;
        }
        if ((kc & 1) == 0) {
            float* row = &scr[((kc >> 1)*32 + o)*33];
            #pragma unroll
            for (int q = 0; q < 8; ++q) {
                row[2*q]      = Svp[q].x;  row[2*q + 1]      = Svp[q].y;
                row[16 + 2*q] = Sv2p[q].x; row[16 + 2*q + 1] = Sv2p[q].y;
            }
            row[32] = S0;
        }
        __syncthreads();

        // ---- reduce 8 groups + stats; thread t handles (oo, pp) ----
        {
            float sm = 0.f, s2 = 0.f, rs = 0.f;
            #pragma unroll
            for (int q = 0; q < 8; ++q) {
                const int b0 = (q*32 + oo)*33;
                sm += scr[b0 + pp];
                s2 += scr[b0 + 16 + pp];
                rs += scr[b0 + 32];
            }
            const float inv = 1.0f / (rs + EPSF);
            const float S1  = rs * inv;
            const float m   = sm * inv;
            float var = s2 * inv - m*m*(2.0f - S1);
            var = fmaxf(var, 0.0f) + EPSF;          // std^2 (+eps inside sqrt)
            meanS[oo*17 + pp] = m;
            i2vS [oo*17 + pp] = 0.5f / var;
            scr[oo*33 + pp] = 0.5f * __logf(var);   // log std; q=0 slot owned by this thread
        }
        __syncthreads();
        if (t < 32) {
            float lsum = 0.f;
            #pragma unroll
            for (int p = 0; p < 16; ++p) lsum += scr[t*33 + p];
            float rs = 0.f;
            #pragma unroll
            for (int q = 0; q < 8; ++q) rs += scr[(q*32 + t)*33 + 32];
            const float cost = (16.0f * bu[t] + lsum) * rs;
            const float ao   = 1.0f / (1.0f + __expf(-lam * (ba[t] - cost)));
            actS[t]  = ao;
            baseS[t] = -lsum - 8.0f*LN2PI + __logf(ao);
        }
        __syncthreads();
    }

#undef LOAD_P
#undef VOTES
#undef M0_BODY
#undef E_BODY

    // ---- output: [mean(512) | act(32)] per n ----
    for (int idx = t; idx < 544; idx += 512) {
        const float v = (idx < 512) ? meanS[(idx >> 4)*17 + (idx & 15)]
                                    : actS[idx - 512];
        out[n*544 + idx] = v;
    }
}

} // namespace

extern "C" void kernel_launch(void* const* d_in, const int* in_sizes, int n_in,
                              void* d_out, int out_size, void* d_ws, size_t ws_size,
                              hipStream_t stream) {
    (void)in_sizes; (void)n_in; (void)out_size;
    const float* x  = (const float*)d_in[0];
    const float* W  = (const float*)d_in[1];
    const float* bu = (const float*)d_in[2];
    const float* ba = (const float*)d_in[3];
    float* out = (float*)d_out;

    const size_t need = (size_t)NKK * 32 * 16 * sizeof(float);  // 2,359,296 B
    if (d_ws != nullptr && ws_size >= need) {
        float* Wt = (float*)d_ws;
        transpose_w<<<dim3(144), dim3(256), 0, stream>>>(W, Wt);
        caps_em_kernel<true><<<dim3(392), dim3(512), 0, stream>>>(
            x, W, (const float4*)Wt, bu, ba, out);
    } else {
        caps_em_kernel<false><<<dim3(392), dim3(512), 0, stream>>>(
            x, W, nullptr, bu, ba, out);
    }
}